// Round 1
// baseline (240.456 us; speedup 1.0000x reference)
//
#include <hip/hip_runtime.h>
#include <math.h>

#define NN 32
#define CC 64
#define HWD 12544
#define HW4 3136
#define HID 8
#define OUTD 256
#define T_INV 0.1f
#define GAMMA_F (12544.0f / 3.0f)

__device__ __forceinline__ float wave_sum(float v) {
    #pragma unroll
    for (int off = 32; off; off >>= 1) v += __shfl_down(v, off, 64);
    return v;
}
__device__ __forceinline__ float wave_max(float v) {
    #pragma unroll
    for (int off = 32; off; off >>= 1) v = fmaxf(v, __shfl_down(v, off, 64));
    return v;
}

// s[n,hw] = sum_c x[n,c,hw] * cw[c] + cb
__global__ __launch_bounds__(256) void k_conv(const float* __restrict__ x,
                                              const float* __restrict__ cw,
                                              const float* __restrict__ cb,
                                              float* __restrict__ s) {
    __shared__ float w[CC];
    int tid = threadIdx.x;
    if (tid < CC) w[tid] = cw[tid];
    __syncthreads();
    int g = blockIdx.x * 256 + tid;          // 0 .. N*HW4-1
    int n = g / HW4;
    int r = g - n * HW4;
    const float4* x4 = (const float4*)x;
    float4 acc = make_float4(0.f, 0.f, 0.f, 0.f);
    long base = (long)(n * CC) * HW4 + r;
    #pragma unroll 8
    for (int c = 0; c < CC; c++) {
        float4 v = x4[base + (long)c * HW4];
        float ww = w[c];
        acc.x += v.x * ww; acc.y += v.y * ww;
        acc.z += v.z * ww; acc.w += v.w * ww;
    }
    float bb = cb[0];
    acc.x += bb; acc.y += bb; acc.z += bb; acc.w += bb;
    ((float4*)s)[g] = acc;
}

// pooled[n,c] = mean over HW
__global__ __launch_bounds__(256) void k_pool(const float* __restrict__ x,
                                              float* __restrict__ pooled) {
    int bid = blockIdx.x;  // n*C + c
    const float4* x4 = (const float4*)x + (long)bid * HW4;
    float acc = 0.f;
    for (int i = threadIdx.x; i < HW4; i += 256) {
        float4 v = x4[i];
        acc += (v.x + v.y) + (v.z + v.w);
    }
    acc = wave_sum(acc);
    __shared__ float lds[4];
    int lane = threadIdx.x & 63, wv = threadIdx.x >> 6;
    if (lane == 0) lds[wv] = acc;
    __syncthreads();
    if (threadIdx.x == 0) {
        pooled[bid] = (lds[0] + lds[1] + lds[2] + lds[3]) * (1.0f / HWD);
    }
}

// per-sample softmax over HW of s/T; overwrite s with spatial = min(gamma*p, 1)
__global__ __launch_bounds__(256) void k_softmax(float* __restrict__ s) {
    int n = blockIdx.x;
    float4* s4 = (float4*)s + (long)n * HW4;
    int tid = threadIdx.x;
    int lane = tid & 63, wv = tid >> 6;
    __shared__ float lds[4];
    __shared__ float bcast;

    float vmax = -3.4e38f;
    for (int i = tid; i < HW4; i += 256) {
        float4 v = s4[i];
        vmax = fmaxf(vmax, fmaxf(fmaxf(v.x, v.y), fmaxf(v.z, v.w)));
    }
    vmax = wave_max(vmax);
    if (lane == 0) lds[wv] = vmax;
    __syncthreads();
    if (tid == 0) bcast = fmaxf(fmaxf(lds[0], lds[1]), fmaxf(lds[2], lds[3]));
    __syncthreads();
    float m = bcast;
    __syncthreads();

    float acc = 0.f;
    for (int i = tid; i < HW4; i += 256) {
        float4 v = s4[i];
        acc += __expf((v.x - m) * T_INV) + __expf((v.y - m) * T_INV)
             + __expf((v.z - m) * T_INV) + __expf((v.w - m) * T_INV);
    }
    acc = wave_sum(acc);
    if (lane == 0) lds[wv] = acc;
    __syncthreads();
    if (tid == 0) bcast = lds[0] + lds[1] + lds[2] + lds[3];
    __syncthreads();
    float scale = GAMMA_F / bcast;

    for (int i = tid; i < HW4; i += 256) {
        float4 v = s4[i];
        v.x = fminf(scale * __expf((v.x - m) * T_INV), 1.f);
        v.y = fminf(scale * __expf((v.y - m) * T_INV), 1.f);
        v.z = fminf(scale * __expf((v.z - m) * T_INV), 1.f);
        v.w = fminf(scale * __expf((v.w - m) * T_INV), 1.f);
        s4[i] = v;
    }
}

// tiny MLP: pooled -> relu(fc1) -> fc2 -> theta -> a,b tables
__global__ __launch_bounds__(256) void k_mlp(const float* __restrict__ pooled,
                                             const float* __restrict__ w1,
                                             const float* __restrict__ b1,
                                             const float* __restrict__ w2,
                                             const float* __restrict__ b2,
                                             float* __restrict__ a_ws,
                                             float* __restrict__ b_ws) {
    int n = blockIdx.x, t = threadIdx.x;
    __shared__ float p[CC];
    __shared__ float h[HID];
    if (t < CC) p[t] = pooled[n * CC + t];
    __syncthreads();
    if (t < HID) {
        float acc = b1[t];
        #pragma unroll 8
        for (int c = 0; c < CC; c++) acc += p[c] * w1[c * HID + t];
        h[t] = fmaxf(acc, 0.f);
    }
    __syncthreads();
    float o = b2[t];
    #pragma unroll
    for (int j = 0; j < HID; j++) o += h[j] * w2[j * OUTD + t];
    float theta = 2.f / (1.f + __expf(-o)) - 1.f;   // 2*sigmoid(o)-1
    int k = t >> 7;            // K index
    int c = (t >> 1) & 63;     // C index
    int d = t & 1;             // 0 = alpha, 1 = beta
    float init = (k == 0) ? 1.f : 0.f;   // init_alpha == init_beta == [1,0]
    int idx = n * 128 + k * 64 + c;      // [N, K, C]
    if (d == 0) a_ws[idx] = init + theta;        // LAMBDA_ALPHA = 1.0
    else        b_ws[idx] = init + 0.5f * theta; // LAMBDA_BETA  = 0.5
}

// out[n,c,hw] = spatial[n,hw] * max(x*a0+b0, x*a1+b1)
__global__ __launch_bounds__(256) void k_final(const float* __restrict__ x,
                                               const float* __restrict__ sp,
                                               const float* __restrict__ a_ws,
                                               const float* __restrict__ b_ws,
                                               float* __restrict__ out) {
    int bid = blockIdx.x;  // n*C + c
    int n = bid >> 6, c = bid & 63;
    float a0 = a_ws[n * 128 + c];
    float b0 = b_ws[n * 128 + c];
    float a1 = a_ws[n * 128 + 64 + c];
    float b1v = b_ws[n * 128 + 64 + c];
    const float4* x4 = (const float4*)x + (long)bid * HW4;
    const float4* sp4 = (const float4*)sp + (long)n * HW4;
    float4* o4 = (float4*)out + (long)bid * HW4;
    for (int i = threadIdx.x; i < HW4; i += 256) {
        float4 xv = x4[i];
        float4 sv = sp4[i];
        float4 r;
        r.x = sv.x * fmaxf(xv.x * a0 + b0, xv.x * a1 + b1v);
        r.y = sv.y * fmaxf(xv.y * a0 + b0, xv.y * a1 + b1v);
        r.z = sv.z * fmaxf(xv.z * a0 + b0, xv.z * a1 + b1v);
        r.w = sv.w * fmaxf(xv.w * a0 + b0, xv.w * a1 + b1v);
        o4[i] = r;
    }
}

extern "C" void kernel_launch(void* const* d_in, const int* in_sizes, int n_in,
                              void* d_out, int out_size, void* d_ws, size_t ws_size,
                              hipStream_t stream) {
    const float* x      = (const float*)d_in[0];
    const float* conv_w = (const float*)d_in[1];
    const float* conv_b = (const float*)d_in[2];
    const float* w1     = (const float*)d_in[3];
    const float* b1     = (const float*)d_in[4];
    const float* w2     = (const float*)d_in[5];
    const float* b2     = (const float*)d_in[6];
    float* out = (float*)d_out;

    float* ws = (float*)d_ws;
    float* s      = ws;                    // N*HW = 401408 floats (reused as spatial)
    float* pooled = s + NN * HWD;          // N*C  = 2048
    float* a_ws   = pooled + NN * CC;      // N*K*C = 4096
    float* b_ws   = a_ws + NN * 2 * CC;    // 4096

    k_conv   <<<(NN * HW4) / 256, 256, 0, stream>>>(x, conv_w, conv_b, s);
    k_pool   <<<NN * CC,          256, 0, stream>>>(x, pooled);
    k_softmax<<<NN,               256, 0, stream>>>(s);
    k_mlp    <<<NN,               256, 0, stream>>>(pooled, w1, b1, w2, b2, a_ws, b_ws);
    k_final  <<<NN * CC,          256, 0, stream>>>(x, s, a_ws, b_ws, out);
}